// Round 19
// baseline (66.040 us; speedup 1.0000x reference)
//
#include <hip/hip_runtime.h>

#define B_N 4096
#define C_N 128
#define E_N 10

#define NM3 165
#define NM2 45
#define NMT 219           // dense m: deg1 0..8, deg2 9..53, deg3 54..218
#define MSPLIT 110        // m < MSPLIT via SMEM lane; m >= MSPLIT via LDS
#define NLDS (NMT - MSPLIT)   // 109 staged deg3 monomials
#define TSTRIDE 224       // float4 stride per (e,c) table (3584 B), dense
#define LIST_BLOCKS 4     // extra m-slots in fused prep for node bucketing

// ws byte offsets
#define WS_CNT    0
#define WS_LIST   64
#define WS_TABLES 212992  // 1024-aligned; tables: 1280 * 224 * 16 = 4,587,520 B

__device__ __forceinline__ void unrank3(int m, int& I, int& J, int& K) {
    int n = 0;
    for (int i = 0; i < 9; ++i)
        for (int j = i; j < 9; ++j)
            for (int k = j; k < 9; ++k) {
                if (n == m) { I = i; J = j; K = k; return; }
                ++n;
            }
}
__device__ __forceinline__ void unrank2(int m, int& I, int& J) {
    int n = 0;
    for (int i = 0; i < 9; ++i)
        for (int j = i; j < 9; ++j) {
            if (n == m) { I = i; J = j; return; }
            ++n;
        }
}

// ---------------------------------------------------------------------------
// Kernel 1 (FUSED prep): grid (NMT+4, E_N) x 128 threads.
//   m < NMT : build table row (m,e) for all 128 channels, symmetrizing U
//             inline. In this (m,e)-grid each block reads ONLY its own
//             monomial's 6 permutation rows (block-uniform -> s_load,
//             L2-hot across e) — unlike R12's failed (c,e)-grid fusion.
//   m >= NMT: bucket nodes by element (slice (m-NMT)*10+e of 128 nodes).
// Table[(e*128+c)*224 + m] = float4(s, v0, v1, v2); m dense 0..218.
// ---------------------------------------------------------------------------
__global__ __launch_bounds__(128) void fused_prep_kernel(
    const float* __restrict__ y, int* __restrict__ cnt, int* __restrict__ list,
    const float* __restrict__ U1s, const float* __restrict__ U2s, const float* __restrict__ U3s,
    const float* __restrict__ W1s, const float* __restrict__ W2s, const float* __restrict__ W3s,
    const float* __restrict__ U1v, const float* __restrict__ U2v, const float* __restrict__ U3v,
    const float* __restrict__ W1v, const float* __restrict__ W2v, const float* __restrict__ W3v,
    float* __restrict__ tables)
{
    const int m = blockIdx.x;   // 0..NMT+LIST_BLOCKS-1
    const int e = blockIdx.y;   // 0..9
    const int c = threadIdx.x;  // 0..127

    if (m >= NMT) {
        // ---- node bucketing ----
        int b = ((m - NMT) * E_N + e) * 128 + c;   // 0..5119
        if (b >= B_N) return;
        const float* yb = y + (size_t)b * E_N;
        int el = 0;
#pragma unroll
        for (int j = 1; j < E_N; ++j) el = (yb[j] > 0.5f) ? j : el;
        int pos = atomicAdd(&cnt[el], 1);
        list[el * B_N + pos] = b;
        return;
    }

    // ---- table row (m,e): inline symmetrization ----
    float4 t;
    if (m < 9) {
        t.x = U1s[m]      * W1s[e * C_N + c];
        t.y = U1v[m]      * W1v[e * C_N + c];
        t.z = U1v[9 + m]  * W1v[e * C_N + c];
        t.w = U1v[18 + m] * W1v[e * C_N + c];
    } else if (m < 9 + NM2) {
        const int mm = m - 9;
        int i, j; unrank2(mm, i, j);
        const float sc = (i == j) ? 0.5f : 1.f;
        float s = 0.f;
#pragma unroll
        for (int k = 0; k < 3; ++k) {
            float u = (U2s[(i * 9 + j) * 3 + k] + U2s[(j * 9 + i) * 3 + k]) * sc;
            s = fmaf(u, W2s[(e * 3 + k) * C_N + c], s);
        }
        t.x = s;
        float tv[3];
#pragma unroll
        for (int a = 0; a < 3; ++a) {
            float sv = 0.f;
#pragma unroll
            for (int k = 0; k < 4; ++k) {
                float u = (U2v[((a * 9 + i) * 9 + j) * 4 + k] +
                           U2v[((a * 9 + j) * 9 + i) * 4 + k]) * sc;
                sv = fmaf(u, W2v[(e * 4 + k) * C_N + c], sv);
            }
            tv[a] = sv;
        }
        t.y = tv[0]; t.z = tv[1]; t.w = tv[2];
    } else {
        const int mm = m - (9 + NM2);
        int i, j, k3; unrank3(mm, i, j, k3);
        const float sc = (i == k3) ? (1.f / 6.f) : ((i == j || j == k3) ? 0.5f : 1.f);
#define U3SE(a,b,cc,kk) U3s[((((a)*9+(b))*9+(cc))*23) + (kk)]
        float s = 0.f;
#pragma unroll
        for (int k = 0; k < 23; ++k) {
            float u = (U3SE(i,j,k3,k) + U3SE(i,k3,j,k) + U3SE(j,i,k3,k) +
                       U3SE(j,k3,i,k) + U3SE(k3,i,j,k) + U3SE(k3,j,i,k)) * sc;
            s = fmaf(u, W3s[(e * 23 + k) * C_N + c], s);
        }
        t.x = s;
#define U3VE(a,p,b,cc,kk) U3v[(((((a)*9+(p))*9+(b))*9+(cc))*15) + (kk)]
        float tv[3];
#pragma unroll
        for (int a = 0; a < 3; ++a) {
            float sv = 0.f;
#pragma unroll
            for (int k = 0; k < 15; ++k) {
                float u = (U3VE(a,i,j,k3,k) + U3VE(a,i,k3,j,k) + U3VE(a,j,i,k3,k) +
                           U3VE(a,j,k3,i,k) + U3VE(a,k3,i,j,k) + U3VE(a,k3,j,i,k)) * sc;
                sv = fmaf(u, W3v[(e * 15 + k) * C_N + c], sv);
            }
            tv[a] = sv;
        }
        t.y = tv[0]; t.z = tv[1]; t.w = tv[2];
    }
    ((float4*)tables)[(size_t)(e * C_N + c) * TSTRIDE + m] = t;
}

// ---------------------------------------------------------------------------
// Kernel 2 (R17-proven main, fp32, verbatim): async-staged dual-pipe walk,
// NB=1. The LDS-tail global load issues first (registers), the SMEM
// deg1+deg2 phases run while it flies, then ds_write + barrier, then the
// deg3 nest (first 56 via SMEM, last 109 via LDS).
// ---------------------------------------------------------------------------
__global__ __launch_bounds__(256) void sc_main_kernel(
    const float* __restrict__ x,
    const int* __restrict__ cnt, const int* __restrict__ list,
    const float* __restrict__ tables,
    float* __restrict__ out)
{
    const int c     = blockIdx.x;   // 0..127
    const int e     = blockIdx.y;   // 0..9
    const int chunk = blockIdx.z;   // 0..3

    const int n = cnt[e];
    if (chunk * 256 >= n) return;   // block-uniform exit (pre-barrier)

    __shared__ float Tx[NLDS], Ty[NLDS], Tz[NLDS], Tw[NLDS];
    const int tid = threadIdx.x;

    const float4* __restrict__ T =
        (const float4*)tables + (size_t)(e * C_N + c) * TSTRIDE;   // block-uniform

    // ---- issue LDS-tail staging load early (plain global -> regs) ----
    float4 stg = make_float4(0.f, 0.f, 0.f, 0.f);
    if (tid < NLDS) stg = T[MSPLIT + tid];

    const int idx = chunk * 256 + tid;
    const bool active = idx < n;
    const int cl = active ? idx : n - 1;
    const int b = list[e * B_N + cl];

    float xr[9];
    float ax = 0.f, ay = 0.f, az = 0.f, aw = 0.f;

    if (active) {
        const float* xp = x + ((size_t)b * C_N + c) * 9;
#pragma unroll
        for (int i = 0; i < 9; ++i) xr[i] = xp[i];

        // ---- degree 1: m = 0..8 (SMEM) ----
#pragma unroll
        for (int i = 0; i < 9; ++i) {
            float4 t = T[i];
            float q = xr[i];
            ax = fmaf(t.x, q, ax);
            ay = fmaf(t.y, q, ay);
            az = fmaf(t.z, q, az);
            aw = fmaf(t.w, q, aw);
        }

        // ---- degree 2: m = 9..53 (SMEM), ascending pair order ----
        int m2 = 9;
#pragma unroll
        for (int i = 0; i < 9; ++i) {
#pragma unroll
            for (int j = i; j < 9; ++j) {
                float4 t = T[m2++];
                float p = xr[i] * xr[j];
                ax = fmaf(t.x, p, ax);
                ay = fmaf(t.y, p, ay);
                az = fmaf(t.z, p, az);
                aw = fmaf(t.w, p, aw);
            }
        }
    }

    // ---- write staged tail to LDS, then barrier ----
    if (tid < NLDS) {
        Tx[tid] = stg.x; Ty[tid] = stg.y; Tz[tid] = stg.z; Tw[tid] = stg.w;
    }
    __syncthreads();

    if (!active) return;

    // ---- degree 3: m = 54..218 ascending; m<110 SMEM, m>=110 LDS ----
    int m3 = 54;
#pragma unroll
    for (int i = 0; i < 9; ++i) {
#pragma unroll
        for (int j = i; j < 9; ++j) {
            float p = xr[i] * xr[j];
#pragma unroll
            for (int k = j; k < 9; ++k) {
                float q = p * xr[k];
                if (m3 < MSPLIT) {          // compile-time after full unroll
                    float4 t = T[m3];
                    ax = fmaf(t.x, q, ax);
                    ay = fmaf(t.y, q, ay);
                    az = fmaf(t.z, q, az);
                    aw = fmaf(t.w, q, aw);
                } else {
                    int s = m3 - MSPLIT;
                    ax = fmaf(Tx[s], q, ax);
                    ay = fmaf(Ty[s], q, ay);
                    az = fmaf(Tz[s], q, az);
                    aw = fmaf(Tw[s], q, aw);
                }
                ++m3;
            }
        }
    }

    float* o = out + (size_t)b * 512;
    o[c] = ax;
    o[128 + c * 3 + 0] = ay;
    o[128 + c * 3 + 1] = az;
    o[128 + c * 3 + 2] = aw;
}

// ---------------------------------------------------------------------------
extern "C" void kernel_launch(void* const* d_in, const int* in_sizes, int n_in,
                              void* d_out, int out_size, void* d_ws, size_t ws_size,
                              hipStream_t stream) {
    const float* x   = (const float*)d_in[0];
    const float* y   = (const float*)d_in[1];
    const float* U1s = (const float*)d_in[2];
    const float* U2s = (const float*)d_in[3];
    const float* U3s = (const float*)d_in[4];
    const float* W1s = (const float*)d_in[5];
    const float* W2s = (const float*)d_in[6];
    const float* W3s = (const float*)d_in[7];
    const float* U1v = (const float*)d_in[8];
    const float* U2v = (const float*)d_in[9];
    const float* U3v = (const float*)d_in[10];
    const float* W1v = (const float*)d_in[11];
    const float* W2v = (const float*)d_in[12];
    const float* W3v = (const float*)d_in[13];
    float* out = (float*)d_out;

    int*   cnt    = (int*)((char*)d_ws + WS_CNT);
    int*   list   = (int*)((char*)d_ws + WS_LIST);
    float* tables = (float*)((char*)d_ws + WS_TABLES);

    hipMemsetAsync(d_ws, 0, 64, stream);
    fused_prep_kernel<<<dim3(NMT + LIST_BLOCKS, E_N), dim3(128), 0, stream>>>(
        y, cnt, list,
        U1s, U2s, U3s, W1s, W2s, W3s,
        U1v, U2v, U3v, W1v, W2v, W3v, tables);
    sc_main_kernel<<<dim3(128, E_N, 4), dim3(256), 0, stream>>>(
        x, cnt, list, tables, out);
}